// Round 7
// baseline (823.329 us; speedup 1.0000x reference)
//
#include <hip/hip_runtime.h>
#include <hip/hip_bf16.h>

#define NN 100000
#define NROWS_PAD 100032
#define EE 1600000
#define GG 512
#define SCAN_CHUNK 512
#define SCAN_BLOCKS ((NN + SCAN_CHUNK - 1) / SCAN_CHUNK)   // 196
#define NPB 256                                            // nodes per bucket
#define NB  ((NN + NPB - 1) / NPB)                         // 391 buckets
#define PCHUNK 4096                                        // edges per partition block
#define PBLOCKS ((EE + PCHUNK - 1) / PCHUNK)               // 391
static constexpr float BN_EPS = 1e-5f;

typedef _Float16 half8 __attribute__((ext_vector_type(8)));
typedef float floatx4 __attribute__((ext_vector_type(4)));

// ---------------------------------------------------------------------------
// CSR build (write-local). ebuf packed: src (bits 0-16) | (dst&255) << 17
// ---------------------------------------------------------------------------

__global__ __launch_bounds__(256) void k_bhist(const int* __restrict__ EI,
                                               int* __restrict__ bcount)
{
    __shared__ int h[NB];
    const int t = threadIdx.x;
    for (int i = t; i < NB; i += 256) h[i] = 0;
    __syncthreads();
    const int e0 = blockIdx.x * PCHUNK;
    const int e1 = (e0 + PCHUNK < EE) ? e0 + PCHUNK : EE;
    for (int e = e0 + t; e < e1; e += 256)
        atomicAdd(&h[EI[EE + e] >> 8], 1);
    __syncthreads();
    for (int i = t; i < NB; i += 256)
        if (h[i]) atomicAdd(&bcount[i], h[i]);
}

__global__ __launch_bounds__(512) void k_bscan(const int* __restrict__ bcount,
                                               int* __restrict__ bstart,
                                               int* __restrict__ bcursor)
{
    __shared__ int s[512];
    int t = threadIdx.x;
    int v = (t < NB) ? bcount[t] : 0;
    s[t] = v;
    __syncthreads();
    for (int off = 1; off < 512; off <<= 1) {
        int u = (t >= off) ? s[t - off] : 0;
        __syncthreads();
        s[t] += u;
        __syncthreads();
    }
    if (t < NB) { int ex = s[t] - v; bstart[t] = ex; bcursor[t] = ex; }
    if (t == 0) bstart[NB] = EE;
}

__global__ __launch_bounds__(256) void k_part(const int* __restrict__ EI,
                                              int* __restrict__ bcursor,
                                              int* __restrict__ ebuf)
{
    __shared__ int h[NB];
    __shared__ int cur[NB];
    const int t = threadIdx.x;
    for (int i = t; i < NB; i += 256) h[i] = 0;
    __syncthreads();
    const int e0 = blockIdx.x * PCHUNK;
    const int e1 = (e0 + PCHUNK < EE) ? e0 + PCHUNK : EE;
    for (int e = e0 + t; e < e1; e += 256)
        atomicAdd(&h[EI[EE + e] >> 8], 1);
    __syncthreads();
    for (int i = t; i < NB; i += 256)
        cur[i] = h[i] ? atomicAdd(&bcursor[i], h[i]) : 0;
    __syncthreads();
    for (int e = e0 + t; e < e1; e += 256) {
        int s = EI[e], d = EI[EE + e];
        int pos = atomicAdd(&cur[d >> 8], 1);
        ebuf[pos] = s | ((d & (NPB - 1)) << 17);
    }
}

__global__ __launch_bounds__(256) void k_nhist(const int* __restrict__ ebuf,
                                               const int* __restrict__ bstart,
                                               int* __restrict__ hist)
{
    __shared__ int cnt[NPB];
    const int b = blockIdx.x, t = threadIdx.x;
    cnt[t] = 0;
    __syncthreads();
    const int e0 = bstart[b], e1 = bstart[b + 1];
    for (int e = e0 + t; e < e1; e += 256) {
        unsigned p = (unsigned)__builtin_nontemporal_load(&ebuf[e]);
        atomicAdd(&cnt[p >> 17], 1);
    }
    __syncthreads();
    int idx = b * NPB + t;
    if (idx < NN) hist[idx] = cnt[t];
}

__global__ __launch_bounds__(256) void k_scan1(const int* __restrict__ hist,
                                               int* __restrict__ partials)
{
    __shared__ int red[256];
    int b = blockIdx.x, t = threadIdx.x;
    int i0 = b * SCAN_CHUNK + 2 * t;
    int e0 = (i0 < NN) ? hist[i0] : 0;
    int e1 = (i0 + 1 < NN) ? hist[i0 + 1] : 0;
    red[t] = e0 + e1;
    __syncthreads();
    for (int off = 128; off > 0; off >>= 1) {
        if (t < off) red[t] += red[t + off];
        __syncthreads();
    }
    if (t == 0) partials[b] = red[0];
}

__global__ __launch_bounds__(256) void k_scan2(const int* __restrict__ partials,
                                               int* __restrict__ poffs,
                                               int* __restrict__ row_start)
{
    __shared__ int s[256];
    int t = threadIdx.x;
    int v = (t < SCAN_BLOCKS) ? partials[t] : 0;
    s[t] = v;
    __syncthreads();
    for (int off = 1; off < 256; off <<= 1) {
        int u = (t >= off) ? s[t - off] : 0;
        __syncthreads();
        s[t] += u;
        __syncthreads();
    }
    if (t < SCAN_BLOCKS) poffs[t] = s[t] - v;
    if (t == 0) row_start[NN] = EE;
}

__global__ __launch_bounds__(256) void k_scan3(const int* __restrict__ hist,
                                               const int* __restrict__ poffs,
                                               int* __restrict__ row_start)
{
    __shared__ int s[256];
    int b = blockIdx.x, t = threadIdx.x;
    int i0 = b * SCAN_CHUNK + 2 * t;
    int e0 = (i0 < NN) ? hist[i0] : 0;
    int e1 = (i0 + 1 < NN) ? hist[i0 + 1] : 0;
    int pair = e0 + e1;
    s[t] = pair;
    __syncthreads();
    for (int off = 1; off < 256; off <<= 1) {
        int u = (t >= off) ? s[t - off] : 0;
        __syncthreads();
        s[t] += u;
        __syncthreads();
    }
    int base = poffs[b] + s[t] - pair;
    if (i0 < NN)     row_start[i0] = base;
    if (i0 + 1 < NN) row_start[i0 + 1] = base + e0;
}

__global__ __launch_bounds__(256) void k_fill2(const int* __restrict__ ebuf,
                                               const int* __restrict__ bstart,
                                               const int* __restrict__ row_start,
                                               int* __restrict__ ssrc)
{
    __shared__ int cur[NPB];
    const int b = blockIdx.x, t = threadIdx.x;
    int idx = b * NPB + t;
    cur[t] = (idx < NN) ? row_start[idx] : 0;
    __syncthreads();
    const int e0 = bstart[b], e1 = bstart[b + 1];
    for (int e = e0 + t; e < e1; e += 256) {
        unsigned p = (unsigned)__builtin_nontemporal_load(&ebuf[e]);
        int pos = atomicAdd(&cur[p >> 17], 1);
        ssrc[pos] = (int)(p & 0x1FFFFu);
    }
}

// ---------------------------------------------------------------------------
// x cast + per-layer weight prep (BN scale/shift computed inline from stats)
// ---------------------------------------------------------------------------

__global__ __launch_bounds__(256) void k_xcast(const float* __restrict__ X,
                                               _Float16* __restrict__ Xh)
{
    int idx = blockIdx.x * 256 + threadIdx.x;
    const float4* src = (const float4*)X;
    float4 a = src[idx * 2], b = src[idx * 2 + 1];
    half8 o = { (_Float16)a.x, (_Float16)a.y, (_Float16)a.z, (_Float16)a.w,
                (_Float16)b.x, (_Float16)b.y, (_Float16)b.z, (_Float16)b.w };
    *(half8*)&Xh[idx * 8] = o;
}

__device__ __forceinline__ void bn_sc_sh(const float* colsum, const float* colsq,
                                         const float* g, const float* be, int k,
                                         float& sc, float& sh)
{
    float inv_n = 1.0f / (float)NN;
    float mu = colsum[k] * inv_n;
    float var = colsq[k] * inv_n - mu * mu;
    sc = g[k] * rsqrtf(var + BN_EPS);
    sh = be[k] - mu * sc;
}

// blocks 0-63: Wt1 ([n][k], BN-folded or embed slice); 64-127: Wt2; 128: cvec
__global__ __launch_bounds__(256) void k_prep(
    const float* __restrict__ W1, const float* __restrict__ W2,
    const float* __restrict__ colsum, const float* __restrict__ colsq,
    const float* __restrict__ g, const float* __restrict__ be,
    _Float16* __restrict__ Wt1, _Float16* __restrict__ Wt2,
    float* __restrict__ cvec, int l)
{
    int b = blockIdx.x, t = threadIdx.x;
    if (b < 64) {
        int idx = b * 256 + t;
        int n = idx >> 7, k = idx & 127;
        if (l == 0) {
            Wt1[idx] = (_Float16)W1[(200 + k) * 128 + n];
        } else {
            float sc, sh;
            bn_sc_sh(colsum, colsq, g, be, k, sc, sh);
            Wt1[idx] = (_Float16)(sc * W1[k * 128 + n]);
        }
    } else if (b < 128) {
        int idx = (b - 64) * 256 + t;
        int n = idx >> 7, k = idx & 127;
        Wt2[idx] = (_Float16)W2[k * 128 + n];
    } else if (t < 128) {
        float acc = 0.f;
        if (l != 0) {
            for (int k = 0; k < 128; ++k) {
                float sc, sh;
                bn_sc_sh(colsum, colsq, g, be, k, sc, sh);
                acc = fmaf(sh, W1[k * 128 + t], acc);
            }
        }
        cvec[t] = acc;
    }
}

// ---------------------------------------------------------------------------
// MFMA GEMM (A from global fp16, B-frags direct from L2-hot Wt[n][k])
// block 64x128, 4 waves 2x2, wave tile 32x64
// ---------------------------------------------------------------------------

#define MM_CORE_G(Ah, Wth)                                                   \
    const int lane = tid & 63;                                               \
    const int wv = tid >> 6;                                                 \
    const int ml = lane & 15;                                                \
    const int quad = lane >> 4;                                              \
    const int wr = wv >> 1, wc = wv & 1;                                     \
    floatx4 acc[2][4];                                                       \
    for (int r = 0; r < 2; ++r)                                              \
        for (int t = 0; t < 4; ++t)                                          \
            acc[r][t] = (floatx4){0.f, 0.f, 0.f, 0.f};                       \
    {                                                                        \
        const size_t ar0 = (size_t)(row0 + 32 * wr + ml) * 128;              \
        const size_t ar1 = ar0 + (size_t)16 * 128;                           \
        _Pragma("unroll")                                                    \
        for (int kq = 0; kq < 4; ++kq) {                                     \
            int k0 = kq * 32;                                                \
            half8 a0 = *(const half8*)&Ah[ar0 + k0 + quad * 8];              \
            half8 a1 = *(const half8*)&Ah[ar1 + k0 + quad * 8];              \
            _Pragma("unroll")                                                \
            for (int t = 0; t < 4; ++t) {                                    \
                half8 bf = *(const half8*)&Wth[(size_t)(64 * wc + 16 * t + ml) * 128 + k0 + quad * 8]; \
                acc[0][t] = __builtin_amdgcn_mfma_f32_16x16x32_f16(a0, bf, acc[0][t], 0, 0, 0); \
                acc[1][t] = __builtin_amdgcn_mfma_f32_16x16x32_f16(a1, bf, acc[1][t], 0, 0, 0); \
            }                                                                \
        }                                                                    \
    }

__global__ __launch_bounds__(256) void k_mm_embed(
    const _Float16* __restrict__ Ah, const _Float16* __restrict__ Wth,
    const int* __restrict__ Z, const float* __restrict__ W1,
    _Float16* __restrict__ Ph)
{
    const int tid = threadIdx.x;
    const int row0 = blockIdx.x * 64;
    MM_CORE_G(Ah, Wth)
    #pragma unroll
    for (int r = 0; r < 2; ++r)
        #pragma unroll
        for (int j = 0; j < 4; ++j) {
            int grow = row0 + 32 * wr + 16 * r + quad * 4 + j;
            if (grow < NN) {
                int zv = Z[grow];
                const float* w0 = &W1[zv * 128];
                const float* w1 = &W1[(100 + zv) * 128];
                #pragma unroll
                for (int t = 0; t < 4; ++t) {
                    int gcol = 64 * wc + 16 * t + ml;
                    float v = acc[r][t][j] + w0[gcol] + w1[gcol];
                    Ph[(size_t)grow * 128 + gcol] = (_Float16)v;
                }
            }
        }
}

__global__ __launch_bounds__(256) void k_mm1(
    const _Float16* __restrict__ Ah, const _Float16* __restrict__ Wth,
    _Float16* __restrict__ Ph)
{
    const int tid = threadIdx.x;
    const int row0 = blockIdx.x * 64;
    MM_CORE_G(Ah, Wth)
    #pragma unroll
    for (int r = 0; r < 2; ++r)
        #pragma unroll
        for (int j = 0; j < 4; ++j) {
            int grow = row0 + 32 * wr + 16 * r + quad * 4 + j;
            if (grow < NN) {
                #pragma unroll
                for (int t = 0; t < 4; ++t) {
                    int gcol = 64 * wc + 16 * t + ml;
                    Ph[(size_t)grow * 128 + gcol] = (_Float16)acc[r][t][j];
                }
            }
        }
}

// ---------------------------------------------------------------------------
// Fused aggregate + GEMM2 + BN stats.
// Phase A: 4 lanes/node x 64 nodes gather (32 cols/lane, 4-edge unroll
//          -> 16 outstanding 16B loads/lane) -> relu -> LDS M-tile.
// Phase B: MFMA from LDS A-tile, global B-frags; epilogue stores A (fp16)
//          and accumulates colsum/colsq.
// ---------------------------------------------------------------------------

__global__ __launch_bounds__(256) void k_aggmm2(
    const _Float16* __restrict__ Ph, const int* __restrict__ row_start,
    const int* __restrict__ ssrc, const float* __restrict__ b1,
    const float* __restrict__ cvec, const _Float16* __restrict__ Wt2,
    const float* __restrict__ b2, _Float16* __restrict__ Oh,
    float* __restrict__ colsum, float* __restrict__ colsq)
{
    __shared__ _Float16 Mt[64][130];   // pad 130: ~2-way banks for b128 r/w
    __shared__ float cs[128];
    __shared__ float cq[128];
    const int tid = threadIdx.x;
    const int row0 = blockIdx.x * 64;

    // ---- Phase A: gather ----
    {
        const int nrow = tid >> 2;          // 0..63
        const int node = row0 + nrow;
        const int c0 = (tid & 3) * 32;      // col chunk base
        float ga[32];
        if (node < NN) {
            int s0 = row_start[node], s1 = row_start[node + 1];
            float degp1 = (float)(s1 - s0 + 1);
            #pragma unroll
            for (int c = 0; c < 4; ++c) {
                half8 pv = *(const half8*)&Ph[(size_t)node * 128 + c0 + c * 8];
                #pragma unroll
                for (int j = 0; j < 8; ++j)
                    ga[c * 8 + j] = (float)pv[j]
                        + fmaf(degp1, cvec[c0 + c * 8 + j], b1[c0 + c * 8 + j]);
            }
            int e = s0;
            for (; e + 3 < s1; e += 4) {
                int sa = __builtin_nontemporal_load(&ssrc[e]);
                int sb = __builtin_nontemporal_load(&ssrc[e + 1]);
                int sc_ = __builtin_nontemporal_load(&ssrc[e + 2]);
                int sd = __builtin_nontemporal_load(&ssrc[e + 3]);
                const _Float16* pa = &Ph[(size_t)sa * 128 + c0];
                const _Float16* pb = &Ph[(size_t)sb * 128 + c0];
                const _Float16* pc = &Ph[(size_t)sc_ * 128 + c0];
                const _Float16* pd = &Ph[(size_t)sd * 128 + c0];
                #pragma unroll
                for (int c = 0; c < 4; ++c) {
                    half8 va = *(const half8*)&pa[c * 8];
                    half8 vb = *(const half8*)&pb[c * 8];
                    half8 vc = *(const half8*)&pc[c * 8];
                    half8 vd = *(const half8*)&pd[c * 8];
                    #pragma unroll
                    for (int j = 0; j < 8; ++j)
                        ga[c * 8 + j] += ((float)va[j] + (float)vb[j])
                                       + ((float)vc[j] + (float)vd[j]);
                }
            }
            for (; e < s1; ++e) {
                int sa = __builtin_nontemporal_load(&ssrc[e]);
                const _Float16* pa = &Ph[(size_t)sa * 128 + c0];
                #pragma unroll
                for (int c = 0; c < 4; ++c) {
                    half8 va = *(const half8*)&pa[c * 8];
                    #pragma unroll
                    for (int j = 0; j < 8; ++j) ga[c * 8 + j] += (float)va[j];
                }
            }
            #pragma unroll
            for (int c = 0; c < 4; ++c) {
                half8 o;
                #pragma unroll
                for (int j = 0; j < 8; ++j) o[j] = (_Float16)fmaxf(ga[c * 8 + j], 0.f);
                *(half8*)&Mt[nrow][c0 + c * 8] = o;
            }
        } else {
            half8 zz = {};
            #pragma unroll
            for (int c = 0; c < 4; ++c) *(half8*)&Mt[nrow][c0 + c * 8] = zz;
        }
    }
    if (tid < 128) { cs[tid] = 0.f; cq[tid] = 0.f; }
    __syncthreads();

    // ---- Phase B: MFMA (A from LDS, B from global L2-hot Wt2) ----
    const int lane = tid & 63;
    const int wv = tid >> 6;
    const int ml = lane & 15;
    const int quad = lane >> 4;
    const int wr = wv >> 1, wc = wv & 1;
    floatx4 acc[2][4];
    #pragma unroll
    for (int r = 0; r < 2; ++r)
        #pragma unroll
        for (int t = 0; t < 4; ++t) acc[r][t] = (floatx4){0.f, 0.f, 0.f, 0.f};
    #pragma unroll
    for (int kq = 0; kq < 4; ++kq) {
        int k0 = kq * 32;
        half8 a0 = *(const half8*)&Mt[32 * wr + ml][k0 + quad * 8];
        half8 a1 = *(const half8*)&Mt[32 * wr + 16 + ml][k0 + quad * 8];
        #pragma unroll
        for (int t = 0; t < 4; ++t) {
            half8 bf = *(const half8*)&Wt2[(size_t)(64 * wc + 16 * t + ml) * 128 + k0 + quad * 8];
            acc[0][t] = __builtin_amdgcn_mfma_f32_16x16x32_f16(a0, bf, acc[0][t], 0, 0, 0);
            acc[1][t] = __builtin_amdgcn_mfma_f32_16x16x32_f16(a1, bf, acc[1][t], 0, 0, 0);
        }
    }
    float b2v[4];
    #pragma unroll
    for (int t = 0; t < 4; ++t) b2v[t] = b2[64 * wc + 16 * t + ml];
    float st[4] = {0.f, 0.f, 0.f, 0.f};
    float qt[4] = {0.f, 0.f, 0.f, 0.f};
    #pragma unroll
    for (int r = 0; r < 2; ++r)
        #pragma unroll
        for (int j = 0; j < 4; ++j) {
            int grow = row0 + 32 * wr + 16 * r + quad * 4 + j;
            if (grow < NN) {
                #pragma unroll
                for (int t = 0; t < 4; ++t) {
                    int gcol = 64 * wc + 16 * t + ml;
                    float v = fmaxf(acc[r][t][j] + b2v[t], 0.f);
                    Oh[(size_t)grow * 128 + gcol] = (_Float16)v;
                    st[t] += v;
                    qt[t] += v * v;
                }
            }
        }
    #pragma unroll
    for (int t = 0; t < 4; ++t) {
        int gcol = 64 * wc + 16 * t + ml;
        atomicAdd(&cs[gcol], st[t]);
        atomicAdd(&cq[gcol], qt[t]);
    }
    __syncthreads();
    if (tid < 128) {
        atomicAdd(&colsum[tid], cs[tid]);
        atomicAdd(&colsq[tid], cq[tid]);
    }
}

// ---------------------------------------------------------------------------
// mean-pool per graph (BN sc/sh computed inline); 8 row-groups x 16 col-segs
// ---------------------------------------------------------------------------

__global__ __launch_bounds__(128) void k_pool(
    const _Float16* __restrict__ Ah, const int* __restrict__ batch,
    const float* __restrict__ colsum, const float* __restrict__ colsq,
    const float* __restrict__ g_, const float* __restrict__ be,
    float* __restrict__ pooled, int loff)
{
    __shared__ float red[8][128];
    int g = blockIdx.x;
    int t = threadIdx.x;
    int rg = t >> 4, seg = t & 15;
    int lo = 0, hi = NN;
    while (lo < hi) { int mid = (lo + hi) >> 1; if (batch[mid] < g) lo = mid + 1; else hi = mid; }
    int s = lo;
    lo = s; hi = NN;
    while (lo < hi) { int mid = (lo + hi) >> 1; if (batch[mid] < g + 1) lo = mid + 1; else hi = mid; }
    int e = lo;
    float acc[8] = {};
    for (int i = s + rg; i < e; i += 8) {
        half8 v = *(const half8*)&Ah[(size_t)i * 128 + seg * 8];
        #pragma unroll
        for (int j = 0; j < 8; ++j) acc[j] += (float)v[j];
    }
    #pragma unroll
    for (int j = 0; j < 8; ++j) red[rg][seg * 8 + j] = acc[j];
    __syncthreads();
    int cnt = e - s;
    float inv = 1.0f / (float)(cnt > 0 ? cnt : 1);
    if (t < 128) {
        float s_ = 0.f;
        #pragma unroll
        for (int r = 0; r < 8; ++r) s_ += red[r][t];
        float sc, sh;
        bn_sc_sh(colsum, colsq, g_, be, t, sc, sh);
        pooled[g * 384 + loff + t] = fmaf(sc, s_ * inv, sh);
    }
}

__global__ __launch_bounds__(128) void k_final(
    const float* __restrict__ pooled,
    const float* __restrict__ Wl1, const float* __restrict__ bl1,
    const float* __restrict__ Wl2, const float* __restrict__ bl2,
    float* __restrict__ out)
{
    __shared__ float pr[384];
    __shared__ float red[128];
    int g = blockIdx.x, j = threadIdx.x;
    for (int i = j; i < 384; i += 128) pr[i] = pooled[g * 384 + i];
    __syncthreads();
    float acc = bl1[j];
    for (int k = 0; k < 384; ++k) acc = fmaf(pr[k], Wl1[k * 128 + j], acc);
    float r = fmaxf(acc, 0.f) * Wl2[j];
    red[j] = r;
    __syncthreads();
    for (int off = 64; off > 0; off >>= 1) {
        if (j < off) red[j] += red[j + off];
        __syncthreads();
    }
    if (j == 0) out[g] = red[0] + bl2[0];
}

extern "C" void kernel_launch(void* const* d_in, const int* in_sizes, int n_in,
                              void* d_out, int out_size, void* d_ws, size_t ws_size,
                              hipStream_t stream)
{
    const float* x     = (const float*)d_in[0];
    const int*   z     = (const int*)d_in[1];
    const int*   ei    = (const int*)d_in[2];
    const int*   batch = (const int*)d_in[3];
    const float* W1a[3] = {(const float*)d_in[4],  (const float*)d_in[10], (const float*)d_in[16]};
    const float* b1a[3] = {(const float*)d_in[5],  (const float*)d_in[11], (const float*)d_in[17]};
    const float* W2a[3] = {(const float*)d_in[6],  (const float*)d_in[12], (const float*)d_in[18]};
    const float* b2a[3] = {(const float*)d_in[7],  (const float*)d_in[13], (const float*)d_in[19]};
    const float* ga[3]  = {(const float*)d_in[8],  (const float*)d_in[14], (const float*)d_in[20]};
    const float* bea[3] = {(const float*)d_in[9],  (const float*)d_in[15], (const float*)d_in[21]};
    const float* Wl1 = (const float*)d_in[22];
    const float* bl1 = (const float*)d_in[23];
    const float* Wl2 = (const float*)d_in[24];
    const float* bl2 = (const float*)d_in[25];
    float* out = (float*)d_out;

    char* ws = (char*)d_ws;
    size_t off = 0;
    auto alloc = [&](size_t bytes) {
        void* p = ws + off;
        off += (bytes + 255) & ~(size_t)255;
        return p;
    };
    _Float16* Xh  = (_Float16*)alloc((size_t)NROWS_PAD * 128 * 2);
    _Float16* Ph  = (_Float16*)alloc((size_t)NROWS_PAD * 128 * 2);
    _Float16* Ahb = (_Float16*)alloc((size_t)NROWS_PAD * 128 * 2);
    _Float16* Wt1 = (_Float16*)alloc((size_t)128 * 128 * 2);
    _Float16* Wt2 = (_Float16*)alloc((size_t)128 * 128 * 2);
    int*   ebuf     = (int*)alloc((size_t)EE * 4);
    int*   ssrc     = (int*)alloc((size_t)EE * 4);
    int*   hist     = (int*)alloc((size_t)NN * 4);
    int*   row_st   = (int*)alloc((size_t)(NN + 1) * 4);
    int*   bcount   = (int*)alloc((size_t)NB * 4);
    int*   bstart   = (int*)alloc((size_t)(NB + 1) * 4);
    int*   bcursor  = (int*)alloc((size_t)NB * 4);
    int*   partials = (int*)alloc((size_t)SCAN_BLOCKS * 4);
    int*   poffs    = (int*)alloc((size_t)SCAN_BLOCKS * 4);
    float* cvec     = (float*)alloc(128 * 4);
    float* stats    = (float*)alloc(3 * 256 * 4);   // per-layer colsum|colsq
    float* pooled   = (float*)alloc((size_t)GG * 384 * 4);

    const int gemmBlocks = (NN + 63) / 64;           // 1563

    // ---- one-time per call ----
    hipMemsetAsync(stats, 0, 3 * 256 * 4, stream);
    hipMemsetAsync(bcount, 0, (size_t)NB * 4, stream);
    k_xcast<<<(NN * 128 / 8 + 255) / 256, 256, 0, stream>>>(x, Xh);
    k_bhist<<<PBLOCKS, 256, 0, stream>>>(ei, bcount);
    k_bscan<<<1, 512, 0, stream>>>(bcount, bstart, bcursor);
    k_part<<<PBLOCKS, 256, 0, stream>>>(ei, bcursor, ebuf);
    k_nhist<<<NB, 256, 0, stream>>>(ebuf, bstart, hist);
    k_scan1<<<SCAN_BLOCKS, 256, 0, stream>>>(hist, partials);
    k_scan2<<<1, 256, 0, stream>>>(partials, poffs, row_st);
    k_scan3<<<SCAN_BLOCKS, 256, 0, stream>>>(hist, poffs, row_st);
    k_fill2<<<NB, 256, 0, stream>>>(ebuf, bstart, row_st, ssrc);

    for (int l = 0; l < 3; ++l) {
        float* colsum = stats + l * 256;
        float* colsq  = stats + l * 256 + 128;
        const float* psum = (l > 0) ? stats + (l - 1) * 256 : stats;
        const float* psq  = (l > 0) ? stats + (l - 1) * 256 + 128 : stats + 128;
        const float* pg   = (l > 0) ? ga[l - 1] : ga[0];
        const float* pbe  = (l > 0) ? bea[l - 1] : bea[0];
        k_prep<<<129, 256, 0, stream>>>(W1a[l], W2a[l], psum, psq, pg, pbe,
                                        Wt1, Wt2, cvec, l);
        if (l == 0)
            k_mm_embed<<<gemmBlocks, 256, 0, stream>>>(Xh, Wt1, z, W1a[0], Ph);
        else
            k_mm1<<<gemmBlocks, 256, 0, stream>>>(Ahb, Wt1, Ph);
        k_aggmm2<<<gemmBlocks, 256, 0, stream>>>(Ph, row_st, ssrc, b1a[l], cvec,
                                                 Wt2, b2a[l], Ahb, colsum, colsq);
        k_pool<<<GG, 128, 0, stream>>>(Ahb, batch, colsum, colsq, ga[l], bea[l],
                                       pooled, l * 128);
    }
    k_final<<<GG, 128, 0, stream>>>(pooled, Wl1, bl1, Wl2, bl2, out);
}